// Round 1
// baseline (1974.584 us; speedup 1.0000x reference)
//
#include <hip/hip_runtime.h>
#include <hip/hip_bf16.h>

#define E_ 8
#define H_ 2048
#define D_ 4096
#define R_ 8
#define T_ 2048
#define TWO_D_ 8192
#define SCALE_ 2.0f
#define LDSK 40  // padded LDS row stride in bf16 elems (128B rows -> 2-way bank alias, free)

typedef __attribute__((ext_vector_type(8))) short short8;
typedef __attribute__((ext_vector_type(4))) float f32x4;

__device__ __forceinline__ unsigned short f2bf(float f) {
  union { float f; unsigned u; } c; c.f = f;
  unsigned u = c.u + 0x7fffu + ((c.u >> 16) & 1u);  // RNE
  return (unsigned short)(u >> 16);
}
__device__ __forceinline__ float bf2f(unsigned short s) {
  union { unsigned u; float f; } c; c.u = ((unsigned)s) << 16;
  return c.f;
}

// low[tok][r] = sum_i X[tok][i] * A[e][r][i]   (one wave per token, fp32 math)
template <int K, bool XBF16>
__global__ __launch_bounds__(256) void k_low(const void* __restrict__ Xv,
                                             const float* __restrict__ A,
                                             float* __restrict__ low) {
  int wave = (blockIdx.x * 256 + threadIdx.x) >> 6;
  int lane = threadIdx.x & 63;
  int e = wave >> 11;  // / T_
  const float* Ae = A + (long)e * R_ * K;
  float acc[R_] = {0.f,0.f,0.f,0.f,0.f,0.f,0.f,0.f};
  for (int it = 0; it < K / 256; ++it) {
    int i = it * 256 + lane * 4;
    float xv[4];
    if constexpr (!XBF16) {
      const float* x = (const float*)Xv + (long)wave * K;
      f32x4 v = *(const f32x4*)(x + i);
      xv[0]=v[0]; xv[1]=v[1]; xv[2]=v[2]; xv[3]=v[3];
    } else {
      const unsigned short* x = (const unsigned short*)Xv + (long)wave * K;
      ushort4 u = *(const ushort4*)(x + i);
      xv[0]=bf2f(u.x); xv[1]=bf2f(u.y); xv[2]=bf2f(u.z); xv[3]=bf2f(u.w);
    }
    #pragma unroll
    for (int r = 0; r < R_; ++r) {
      f32x4 a = *(const f32x4*)(Ae + r * K + i);
      acc[r] += xv[0]*a[0] + xv[1]*a[1] + xv[2]*a[2] + xv[3]*a[3];
    }
  }
  #pragma unroll
  for (int r = 0; r < R_; ++r) {
    float v = acc[r];
    #pragma unroll
    for (int off = 32; off > 0; off >>= 1) v += __shfl_xor(v, off);
    acc[r] = v;
  }
  if (lane == 0) {
    #pragma unroll
    for (int r = 0; r < R_; ++r) low[(long)wave * R_ + r] = acc[r];
  }
}

// GEMM1: h = up*silu(gate), gate_up = x@Wgu^T + SCALE*low1@Bgu^T. Writes h bf16.
__global__ __launch_bounds__(256, 2) void k_gemm1(
    const float* __restrict__ X, const float* __restrict__ Wgu,
    const float* __restrict__ Bgu, const float* __restrict__ low,
    unsigned short* __restrict__ Hout) {
  __shared__ __align__(16) unsigned short smem[3 * 128 * LDSK];
  unsigned short* sA  = smem;
  unsigned short* sBg = smem + 128 * LDSK;
  unsigned short* sBu = smem + 2 * 128 * LDSK;

  const int MT = T_ / 128;   // 16
  const int NT = D_ / 128;   // 32
  int b = blockIdx.x;
  int cpx = (int)gridDim.x >> 3;
  int swz = (b & 7) * cpx + (b >> 3);        // bijective: grid % 8 == 0
  int e  = swz / (MT * NT);
  int r0 = swz % (MT * NT);
  int nt = r0 / MT, mt = r0 % MT;            // mt fastest -> weight tile shared per XCD chunk

  int tid = threadIdx.x;
  int lane = tid & 63, w = tid >> 6;
  int wr = (w >> 1) * 64, wc = (w & 1) * 64;
  int row0 = tid >> 3;
  int c4 = (tid & 7) * 4;

  const float* Ab  = X   + ((long)(e * T_) + mt * 128 + row0) * H_ + c4;
  const float* Bgb = Wgu + ((long)e * TWO_D_ + nt * 128 + row0) * (long)H_ + c4;
  const float* Bub = Bgb + (long)D_ * H_;

  f32x4 ra[4], rg[4], ru[4];
  f32x4 accg[4][4] = {}, accu[4][4] = {};

  #pragma unroll
  for (int k = 0; k < 4; ++k) {
    ra[k] = *(const f32x4*)(Ab  + (long)k * 32 * H_);
    rg[k] = *(const f32x4*)(Bgb + (long)k * 32 * H_);
    ru[k] = *(const f32x4*)(Bub + (long)k * 32 * H_);
  }

  for (int kt = 0; kt < H_ / 32; ++kt) {
    __syncthreads();
    #pragma unroll
    for (int k = 0; k < 4; ++k) {
      int off = (row0 + k * 32) * LDSK + c4;
      ushort4 a4; a4.x=f2bf(ra[k][0]); a4.y=f2bf(ra[k][1]); a4.z=f2bf(ra[k][2]); a4.w=f2bf(ra[k][3]);
      *(ushort4*)(sA + off) = a4;
      ushort4 g4; g4.x=f2bf(rg[k][0]); g4.y=f2bf(rg[k][1]); g4.z=f2bf(rg[k][2]); g4.w=f2bf(rg[k][3]);
      *(ushort4*)(sBg + off) = g4;
      ushort4 u4; u4.x=f2bf(ru[k][0]); u4.y=f2bf(ru[k][1]); u4.z=f2bf(ru[k][2]); u4.w=f2bf(ru[k][3]);
      *(ushort4*)(sBu + off) = u4;
    }
    __syncthreads();
    if (kt + 1 < H_ / 32) {   // early-issue next tile (T14): latency hides under compute
      int ko = (kt + 1) * 32;
      #pragma unroll
      for (int k = 0; k < 4; ++k) {
        ra[k] = *(const f32x4*)(Ab  + (long)k * 32 * H_ + ko);
        rg[k] = *(const f32x4*)(Bgb + (long)k * 32 * H_ + ko);
        ru[k] = *(const f32x4*)(Bub + (long)k * 32 * H_ + ko);
      }
    }
    int lrow = lane & 15, lk = (lane >> 4) * 8;
    short8 af[4], bg[4], bu[4];
    #pragma unroll
    for (int i = 0; i < 4; ++i) {
      af[i] = *(const short8*)(sA  + (wr + i * 16 + lrow) * LDSK + lk);
      bg[i] = *(const short8*)(sBg + (wc + i * 16 + lrow) * LDSK + lk);
      bu[i] = *(const short8*)(sBu + (wc + i * 16 + lrow) * LDSK + lk);
    }
    #pragma unroll
    for (int mi = 0; mi < 4; ++mi)
      #pragma unroll
      for (int ni = 0; ni < 4; ++ni) {
        accg[mi][ni] = __builtin_amdgcn_mfma_f32_16x16x32_bf16(af[mi], bg[ni], accg[mi][ni], 0, 0, 0);
        accu[mi][ni] = __builtin_amdgcn_mfma_f32_16x16x32_bf16(af[mi], bu[ni], accu[mi][ni], 0, 0, 0);
      }
  }

  // Epilogue: LoRA rank-8 delta + silu, write h bf16
  __syncthreads();
  float* sEpi = (float*)smem;
  {
    const float* lowb = low + ((long)(e * T_) + mt * 128) * R_;
    const float* bgr  = Bgu + ((long)e * TWO_D_ + nt * 128) * R_;
    const float* bur  = Bgu + ((long)e * TWO_D_ + D_ + nt * 128) * R_;
    ((f32x4*)sEpi)[tid]          = *(const f32x4*)(lowb + tid * 4);
    ((f32x4*)(sEpi + 1024))[tid] = *(const f32x4*)(bgr + tid * 4);
    ((f32x4*)(sEpi + 2048))[tid] = *(const f32x4*)(bur + tid * 4);
  }
  __syncthreads();
  int lrow = lane & 15, lq = lane >> 4;
  #pragma unroll
  for (int mi = 0; mi < 4; ++mi) {
    #pragma unroll
    for (int ni = 0; ni < 4; ++ni) {
      int colL = wc + ni * 16 + lrow;
      const float* bg8 = sEpi + 1024 + colL * 8;
      const float* bu8 = sEpi + 2048 + colL * 8;
      #pragma unroll
      for (int j = 0; j < 4; ++j) {
        int tl = wr + mi * 16 + lq * 4 + j;
        const float* lo8 = sEpi + tl * 8;
        float dg = 0.f, du = 0.f;
        #pragma unroll
        for (int r = 0; r < 8; ++r) { dg += lo8[r] * bg8[r]; du += lo8[r] * bu8[r]; }
        float gate = accg[mi][ni][j] + SCALE_ * dg;
        float up   = accu[mi][ni][j] + SCALE_ * du;
        float h = up * (gate / (1.f + __expf(-gate)));
        Hout[((long)(e * T_) + mt * 128 + tl) * D_ + nt * 128 + colL] = f2bf(h);
      }
    }
  }
}

// GEMM2: out = h@Wd^T + SCALE*low2@Bd^T  (fp32 out)
__global__ __launch_bounds__(256, 2) void k_gemm2(
    const unsigned short* __restrict__ Hin, const float* __restrict__ Wd,
    const float* __restrict__ Bd, const float* __restrict__ low,
    float* __restrict__ Out) {
  __shared__ __align__(16) unsigned short smem[2 * 128 * LDSK];
  unsigned short* sA = smem;
  unsigned short* sB = smem + 128 * LDSK;

  const int MT = T_ / 128;  // 16
  const int NT = H_ / 128;  // 16
  int b = blockIdx.x;
  int cpx = (int)gridDim.x >> 3;
  int swz = (b & 7) * cpx + (b >> 3);
  int e  = swz / (MT * NT);
  int r0 = swz % (MT * NT);
  int nt = r0 / MT, mt = r0 % MT;

  int tid = threadIdx.x;
  int lane = tid & 63, w = tid >> 6;
  int wr = (w >> 1) * 64, wc = (w & 1) * 64;

  int arow0 = tid >> 2;          // bf16 A: 4 threads/row, 2 rows per thread (+64)
  int aq = (tid & 3) * 8;
  const unsigned short* Abase = Hin + ((long)(e * T_) + mt * 128 + arow0) * D_ + aq;
  int brow0 = tid >> 3;          // fp32 B: 8 threads/row, 4 rows per thread (+32)
  int bc4 = (tid & 7) * 4;
  const float* Bbase = Wd + ((long)e * H_ + nt * 128 + brow0) * (long)D_ + bc4;

  short8 raw[2]; f32x4 rb[4];
  f32x4 acc[4][4] = {};

  #pragma unroll
  for (int k = 0; k < 2; ++k) raw[k] = *(const short8*)(Abase + (long)k * 64 * D_);
  #pragma unroll
  for (int k = 0; k < 4; ++k) rb[k] = *(const f32x4*)(Bbase + (long)k * 32 * D_);

  for (int kt = 0; kt < D_ / 32; ++kt) {
    __syncthreads();
    #pragma unroll
    for (int k = 0; k < 2; ++k)
      *(short8*)(sA + (arow0 + k * 64) * LDSK + aq) = raw[k];
    #pragma unroll
    for (int k = 0; k < 4; ++k) {
      int off = (brow0 + k * 32) * LDSK + bc4;
      ushort4 b4; b4.x=f2bf(rb[k][0]); b4.y=f2bf(rb[k][1]); b4.z=f2bf(rb[k][2]); b4.w=f2bf(rb[k][3]);
      *(ushort4*)(sB + off) = b4;
    }
    __syncthreads();
    if (kt + 1 < D_ / 32) {
      int ko = (kt + 1) * 32;
      #pragma unroll
      for (int k = 0; k < 2; ++k) raw[k] = *(const short8*)(Abase + (long)k * 64 * D_ + ko);
      #pragma unroll
      for (int k = 0; k < 4; ++k) rb[k] = *(const f32x4*)(Bbase + (long)k * 32 * D_ + ko);
    }
    int lrow = lane & 15, lk = (lane >> 4) * 8;
    short8 af[4], bf[4];
    #pragma unroll
    for (int i = 0; i < 4; ++i) {
      af[i] = *(const short8*)(sA + (wr + i * 16 + lrow) * LDSK + lk);
      bf[i] = *(const short8*)(sB + (wc + i * 16 + lrow) * LDSK + lk);
    }
    #pragma unroll
    for (int mi = 0; mi < 4; ++mi)
      #pragma unroll
      for (int ni = 0; ni < 4; ++ni)
        acc[mi][ni] = __builtin_amdgcn_mfma_f32_16x16x32_bf16(af[mi], bf[ni], acc[mi][ni], 0, 0, 0);
  }

  __syncthreads();
  float* sEpi = (float*)smem;
  {
    const float* lowb = low + ((long)(e * T_) + mt * 128) * R_;
    const float* bdr  = Bd + ((long)e * H_ + nt * 128) * R_;
    ((f32x4*)sEpi)[tid]          = *(const f32x4*)(lowb + tid * 4);
    ((f32x4*)(sEpi + 1024))[tid] = *(const f32x4*)(bdr + tid * 4);
  }
  __syncthreads();
  int lrow = lane & 15, lq = lane >> 4;
  #pragma unroll
  for (int mi = 0; mi < 4; ++mi) {
    #pragma unroll
    for (int ni = 0; ni < 4; ++ni) {
      int colL = wc + ni * 16 + lrow;
      const float* bd8 = sEpi + 1024 + colL * 8;
      #pragma unroll
      for (int j = 0; j < 4; ++j) {
        int tl = wr + mi * 16 + lq * 4 + j;
        const float* lo8 = sEpi + tl * 8;
        float d = 0.f;
        #pragma unroll
        for (int r = 0; r < 8; ++r) d += lo8[r] * bd8[r];
        Out[((long)(e * T_) + mt * 128 + tl) * H_ + nt * 128 + colL] = acc[mi][ni][j] + SCALE_ * d;
      }
    }
  }
}

extern "C" void kernel_launch(void* const* d_in, const int* in_sizes, int n_in,
                              void* d_out, int out_size, void* d_ws, size_t ws_size,
                              hipStream_t stream) {
  const float* x   = (const float*)d_in[0];
  const float* Wgu = (const float*)d_in[1];
  const float* Agu = (const float*)d_in[2];
  const float* Bgu = (const float*)d_in[3];
  const float* Wd  = (const float*)d_in[4];
  const float* Ad  = (const float*)d_in[5];
  const float* Bd  = (const float*)d_in[6];
  float* out = (float*)d_out;

  char* ws = (char*)d_ws;
  unsigned short* hbuf = (unsigned short*)ws;                        // E*T*D bf16 = 128 MiB
  float* low1 = (float*)(ws + (size_t)E_ * T_ * D_ * 2);             // E*T*R fp32
  float* low2 = low1 + E_ * T_ * R_;

  hipLaunchKernelGGL((k_low<H_, false>), dim3(E_ * T_ / 4), dim3(256), 0, stream, (const void*)x, Agu, low1);
  hipLaunchKernelGGL(k_gemm1, dim3(E_ * (T_ / 128) * (D_ / 128)), dim3(256), 0, stream, x, Wgu, Bgu, low1, hbuf);
  hipLaunchKernelGGL((k_low<D_, true>), dim3(E_ * T_ / 4), dim3(256), 0, stream, (const void*)hbuf, Ad, low2);
  hipLaunchKernelGGL(k_gemm2, dim3(E_ * (T_ / 128) * (H_ / 128)), dim3(256), 0, stream, hbuf, Wd, Bd, low2, out);
}